// Round 8
// baseline (188.246 us; speedup 1.0000x reference)
//
#include <hip/hip_runtime.h>

typedef __attribute__((ext_vector_type(8))) short short8;
typedef __attribute__((ext_vector_type(4))) short short4v;
typedef __attribute__((ext_vector_type(4))) float float4v;
typedef __attribute__((ext_vector_type(2))) int int2v;

__device__ __forceinline__ short f2bf(float f) {           // RNE (epilogue/weights)
    union { float f; unsigned u; } v; v.f = f;
    return (short)((v.u + 0x7fffu + ((v.u >> 16) & 1u)) >> 16);
}
__device__ __forceinline__ int pack2(float a, float b) {   // half-up, 2 bf16 in 1 int
    union { float f; unsigned u; } x, y; x.f = a; y.f = b;
    return (int)(((x.u + 0x8000u) >> 16) | ((y.u + 0x8000u) & 0xFFFF0000u));
}

__device__ __forceinline__ float fast_exp2(float x) {
#if __has_builtin(__builtin_amdgcn_exp2f)
    return __builtin_amdgcn_exp2f(x);
#else
    return exp2f(x);
#endif
}

// ---------------- kernel 0: weight transpose+convert (b-frag tiled) ---------
__global__ void wtrans_kernel(const float* __restrict__ Wk, const float* __restrict__ Wq,
                              const float* __restrict__ Wv, short* __restrict__ Wt3T) {
    int idx = blockIdx.x * 256 + threadIdx.x;       // 3*64*768 = 147456
    int p = idx / 12288;
    int rem = idx - p * 12288;
    int kstep = rem / 512;
    int r2 = rem - kstep * 512;
    int lane = r2 >> 3, i = r2 & 7;
    int quad = lane >> 4, l16 = lane & 15;
    int j = p >> 2, nt = p & 3;
    int n = nt * 16 + l16;
    int k = kstep * 32 + quad * 8 + i;
    const float* W = (j == 0) ? Wq : (j == 1 ? Wk : Wv);
    // log2(e)/sqrt(768) folded into Wq -> scores arrive in log2 domain
    float scale = (j == 0) ? 0.05205877f : 1.0f;
    Wt3T[idx] = f2bf(W[k * 64 + n] * scale);
}

// ---------------- kernel 1: QKV projection, barrier-free main loop ----------
__global__ __launch_bounds__(256, 3) void proj_kernel(
    const float* __restrict__ x, const short* __restrict__ Wt3T,
    short* __restrict__ Qs, short* __restrict__ Kb, short* __restrict__ Vtr)
{
    __shared__ alignas(16) short As[24 * 512];      // 24.6 KB; reused for V staging
    const int tid = threadIdx.x;
    const int wave = tid >> 6, lane = tid & 63, quad = lane >> 4, l16 = lane & 15;
    const int m0 = blockIdx.x * 16;
    const int p0 = wave * 3;

    {   // stage x: thread t -> row r=t>>4, float4 at col (t&15)*4 + ch*64
        const int r = tid >> 4, c16 = tid & 15;
        const float* xp = x + (size_t)(m0 + r) * 768 + c16 * 4;
        float4 v[12];
#pragma unroll
        for (int ch = 0; ch < 12; ++ch) v[ch] = *(const float4*)(xp + ch * 64);
#pragma unroll
        for (int ch = 0; ch < 12; ++ch) {
            const int cb = c16 * 4 + ch * 64;
            const int sidx = (cb >> 5) * 512 + ((((cb >> 3) & 3) * 16 + r) << 3) + (cb & 7);
            *(int2v*)&As[sidx] = (int2v){pack2(v[ch].x, v[ch].y), pack2(v[ch].z, v[ch].w)};
        }
    }
    __syncthreads();

    const short* wp0 = Wt3T + (size_t)(p0 + 0) * 12288 + lane * 8;
    const short* wp1 = Wt3T + (size_t)(p0 + 1) * 12288 + lane * 8;
    const short* wp2 = Wt3T + (size_t)(p0 + 2) * 12288 + lane * 8;

    float4v acc0 = (float4v){0.f, 0.f, 0.f, 0.f};
    float4v acc1 = acc0, acc2 = acc0;

#pragma unroll
    for (int it = 0; it < 24; ++it) {
        short8 a = *(const short8*)&As[it * 512 + lane * 8];
        short8 w0 = *(const short8*)(wp0 + it * 512);
        short8 w1 = *(const short8*)(wp1 + it * 512);
        short8 w2 = *(const short8*)(wp2 + it * 512);
        acc0 = __builtin_amdgcn_mfma_f32_16x16x32_bf16(a, w0, acc0, 0, 0, 0);
        acc1 = __builtin_amdgcn_mfma_f32_16x16x32_bf16(a, w1, acc1, 0, 0, 0);
        acc2 = __builtin_amdgcn_mfma_f32_16x16x32_bf16(a, w2, acc2, 0, 0, 0);
    }

    float4v accs[3] = {acc0, acc1, acc2};
#pragma unroll
    for (int t = 0; t < 3; ++t) {
        const int p = p0 + t, j = p >> 2, nt = p & 3;
        if (j < 2) {        // C layout: col=l16, row=quad*4+r
            short* dst = (j == 0) ? Qs : Kb;
#pragma unroll
            for (int r = 0; r < 4; ++r)
                dst[(size_t)(m0 + quad * 4 + r) * 64 + nt * 16 + l16] = f2bf(accs[t][r]);
        }
    }
    __syncthreads();        // everyone done reading As
    short* sm = As;         // [16][72]
#pragma unroll
    for (int t = 0; t < 3; ++t) {
        const int p = p0 + t, nt = p & 3;
        if ((p >> 2) == 2)
#pragma unroll
            for (int r = 0; r < 4; ++r)
                sm[(quad * 4 + r) * 72 + nt * 16 + l16] = f2bf(accs[t][r]);
    }
    __syncthreads();
    {   // all 256 threads: V -> Vtr[b][h][s]
        const int h = tid >> 2, si = (tid & 3) * 4;
        const int b = m0 >> 12, s0 = m0 & 4095;
        short4v tmp;
#pragma unroll
        for (int i = 0; i < 4; ++i) tmp[i] = sm[(si + i) * 72 + h];
        *(short4v*)(Vtr + (size_t)(b * 64 + h) * 4096 + s0 + si) = tmp;
    }
}

// ---------------- kernel 2: flash attention, barrier-free -------------------
// S^T = K·Q^T with K a-frags and V b-frags read DIRECTLY from global (L1/L2-
// resident tiles; frags identical across waves). LDS holds only the wave-
// private P round-trip (32-kv halves, double-buffered). No __syncthreads.
__global__ __launch_bounds__(128, 4) void attn_kernel(
    const short* __restrict__ Qs, const short* __restrict__ Kb, const short* __restrict__ Vt,
    float* __restrict__ out, float* __restrict__ Lsum, int kv_len)
{
    __shared__ alignas(16) short Pl[2][2][32 * 40];  // [wave][half][q 32][kv 32 +8 pad]

    const int tid = threadIdx.x;
    const int wave = tid >> 6, lane = tid & 63, quad = lane >> 4, l16 = lane & 15;
    const int qt = blockIdx.x, b = blockIdx.y, sp = blockIdx.z;
    const int q0 = qt * 64 + wave * 32;      // batch-local q base for this wave
    const int bS = b * 4096;
    const int kv0 = sp * kv_len;

    // Q frags: register layout serves as B-operand (B[k=h][n=q]) for S^T
    short8 qb[2][2];
#pragma unroll
    for (int qt2 = 0; qt2 < 2; ++qt2)
#pragma unroll
        for (int ks = 0; ks < 2; ++ks)
            qb[qt2][ks] = *(const short8*)(Qs + (size_t)(bS + q0 + qt2 * 16 + l16) * 64 + ks * 32 + quad * 8);

    float4v o[2][4];
    float rs[2] = {0.f, 0.f};
#pragma unroll
    for (int qt2 = 0; qt2 < 2; ++qt2)
#pragma unroll
        for (int nt = 0; nt < 4; ++nt) o[qt2][nt] = (float4v){0.f, 0.f, 0.f, 0.f};

    const short* kbase = Kb + (size_t)bS * 64;
    const short* vbase = Vt + (size_t)b * 64 * 4096;

    for (int kt = 0; kt < kv_len; kt += 64) {
        const int kvg = kv0 + kt;
#pragma unroll
        for (int hf = 0; hf < 2; ++hf) {
            short* plh = &Pl[wave][hf][0];
            // S^T = K·Q^T over this 32-kv half (full h=64 depth)
#pragma unroll
            for (int kvt2 = 0; kvt2 < 2; ++kvt2) {
                const short* krow = kbase + (size_t)(kvg + hf * 32 + kvt2 * 16 + l16) * 64 + quad * 8;
                short8 ka0 = *(const short8*)krow;
                short8 ka1 = *(const short8*)(krow + 32);
#pragma unroll
                for (int qt2 = 0; qt2 < 2; ++qt2) {
                    float4v a0 = (float4v){0.f, 0.f, 0.f, 0.f};
                    a0 = __builtin_amdgcn_mfma_f32_16x16x32_bf16(ka0, qb[qt2][0], a0, 0, 0, 0);
                    a0 = __builtin_amdgcn_mfma_f32_16x16x32_bf16(ka1, qb[qt2][1], a0, 0, 0, 0);
                    float p0 = fast_exp2(a0[0]), p1 = fast_exp2(a0[1]);
                    float p2 = fast_exp2(a0[2]), p3 = fast_exp2(a0[3]);
                    rs[qt2] += (p0 + p1) + (p2 + p3);
                    *(int2v*)&plh[(qt2 * 16 + l16) * 40 + kvt2 * 16 + quad * 4] =
                        (int2v){pack2(p0, p1), pack2(p2, p3)};
                }
            }
            // O += P V for this half (V b-frags direct from global)
            short8 bf[4];
#pragma unroll
            for (int nt = 0; nt < 4; ++nt)
                bf[nt] = *(const short8*)(vbase + (size_t)(nt * 16 + l16) * 4096 + kvg + hf * 32 + quad * 8);
#pragma unroll
            for (int qt2 = 0; qt2 < 2; ++qt2) {
                short8 af = *(const short8*)&plh[(qt2 * 16 + l16) * 40 + quad * 8];
#pragma unroll
                for (int nt = 0; nt < 4; ++nt)
                    o[qt2][nt] = __builtin_amdgcn_mfma_f32_16x16x32_bf16(af, bf[nt], o[qt2][nt], 0, 0, 0);
            }
        }
    }

    // row sums: reduce across the 4 quads (same q = l16 within each qt2 tile)
#pragma unroll
    for (int qt2 = 0; qt2 < 2; ++qt2) {
        rs[qt2] += __shfl_xor(rs[qt2], 16);
        rs[qt2] += __shfl_xor(rs[qt2], 32);
    }

#pragma unroll
    for (int qt2 = 0; qt2 < 2; ++qt2) {
#pragma unroll
        for (int nt = 0; nt < 4; ++nt)
#pragma unroll
            for (int r = 0; r < 4; ++r) {
                int qb2 = q0 + qt2 * 16 + quad * 4 + r;
                atomicAdd(&out[(size_t)(bS + qb2) * 64 + nt * 16 + l16], o[qt2][nt][r]);
            }
        if (quad == 0)
            atomicAdd(&Lsum[bS + q0 + qt2 * 16 + l16], rs[qt2]);
    }
}

// ---------------- kernel 3: normalize ----------------
__global__ void normalize_kernel(float* __restrict__ out, const float* __restrict__ Lsum) {
    int idx = blockIdx.x * 256 + threadIdx.x;   // 1048576
    out[idx] /= Lsum[idx >> 6];
}

extern "C" void kernel_launch(void* const* d_in, const int* in_sizes, int n_in,
                              void* d_out, int out_size, void* d_ws, size_t ws_size,
                              hipStream_t stream) {
    const float* x  = (const float*)d_in[0];
    const float* Wk = (const float*)d_in[1];
    const float* Wq = (const float*)d_in[2];
    const float* Wv = (const float*)d_in[3];
    float* out = (float*)d_out;

    char* w = (char*)d_ws;
    size_t off = 0;
    auto take = [&](size_t bytes) -> void* {
        void* p = w + off;
        off = (off + bytes + 255) & ~(size_t)255;
        return p;
    };
    short* Qs   = (short*)take((size_t)16384 * 64 * 2);
    short* Kb   = (short*)take((size_t)16384 * 64 * 2);
    short* Vt   = (short*)take((size_t)16384 * 64 * 2);
    short* Wt3  = (short*)take((size_t)3 * 64 * 768 * 2);
    float* Lsum = (float*)take((size_t)16384 * 4);

    hipMemsetAsync(out, 0, (size_t)out_size * sizeof(float), stream);
    hipMemsetAsync(Lsum, 0, (size_t)16384 * 4, stream);

    wtrans_kernel<<<576, 256, 0, stream>>>(Wk, Wq, Wv, Wt3);
    proj_kernel<<<1024, 256, 0, stream>>>(x, Wt3, Qs, Kb, Vt);
    const int nsplit = 8;
    dim3 ag(64, 4, nsplit);
    attn_kernel<<<ag, 128, 0, stream>>>(Qs, Kb, Vt, out, Lsum, 4096 / nsplit);
    normalize_kernel<<<4096, 256, 0, stream>>>(out, Lsum);
}

// Round 9
// 153.875 us; speedup vs baseline: 1.2234x; 1.2234x over previous
//
#include <hip/hip_runtime.h>

typedef __attribute__((ext_vector_type(8))) short short8;
typedef __attribute__((ext_vector_type(4))) short short4v;
typedef __attribute__((ext_vector_type(4))) float float4v;
typedef __attribute__((ext_vector_type(2))) int int2v;

__device__ __forceinline__ short f2bf(float f) {           // RNE (epilogue/weights)
    union { float f; unsigned u; } v; v.f = f;
    return (short)((v.u + 0x7fffu + ((v.u >> 16) & 1u)) >> 16);
}
__device__ __forceinline__ int pack2(float a, float b) {   // half-up, 2 bf16 in 1 int
    union { float f; unsigned u; } x, y; x.f = a; y.f = b;
    return (int)(((x.u + 0x8000u) >> 16) | ((y.u + 0x8000u) & 0xFFFF0000u));
}

__device__ __forceinline__ float fast_exp2(float x) {
#if __has_builtin(__builtin_amdgcn_exp2f)
    return __builtin_amdgcn_exp2f(x);
#else
    return exp2f(x);
#endif
}

// ---------------- kernel 0: weight transpose+convert (b-frag tiled) ---------
__global__ void wtrans_kernel(const float* __restrict__ Wk, const float* __restrict__ Wq,
                              const float* __restrict__ Wv, short* __restrict__ Wt3T) {
    int idx = blockIdx.x * 256 + threadIdx.x;       // 3*64*768 = 147456
    int p = idx / 12288;
    int rem = idx - p * 12288;
    int kstep = rem / 512;
    int r2 = rem - kstep * 512;
    int lane = r2 >> 3, i = r2 & 7;
    int quad = lane >> 4, l16 = lane & 15;
    int j = p >> 2, nt = p & 3;
    int n = nt * 16 + l16;
    int k = kstep * 32 + quad * 8 + i;
    const float* W = (j == 0) ? Wq : (j == 1 ? Wk : Wv);
    // log2(e)/sqrt(768) folded into Wq -> scores arrive in log2 domain
    float scale = (j == 0) ? 0.05205877f : 1.0f;
    Wt3T[idx] = f2bf(W[k * 64 + n] * scale);
}

// ---------------- kernel 1: QKV projection ----------------------------------
// Main loop unchanged (barrier-free N-split). Epilogue now emits K and V in
// fragment-tiled layouts so attn can load fragments as contiguous 1KB chunks:
//   Kf[((b*256 + s/16)*2 + ks)*512 + lane*8 + j] = K[s16+l16][ks*32+quad*8+j]
//   Vf[((b*128 + s/32)*4 + nt)*512 + lane*8 + j] = V[32blk: quad*8+j][nt*16+l16]
__global__ __launch_bounds__(256, 3) void proj_kernel(
    const float* __restrict__ x, const short* __restrict__ Wt3T,
    short* __restrict__ Qs, short* __restrict__ Kf, short* __restrict__ Vf)
{
    __shared__ alignas(16) short As[24 * 512];      // 24.6 KB; reused for K/V staging
    const int tid = threadIdx.x;
    const int wave = tid >> 6, lane = tid & 63, quad = lane >> 4, l16 = lane & 15;
    const int m0 = blockIdx.x * 16;
    const int p0 = wave * 3;
    const int b = m0 >> 12, s0 = m0 & 4095;

    {   // stage x: thread t -> row r=t>>4, float4 at col (t&15)*4 + ch*64
        const int r = tid >> 4, c16 = tid & 15;
        const float* xp = x + (size_t)(m0 + r) * 768 + c16 * 4;
        float4 v[12];
#pragma unroll
        for (int ch = 0; ch < 12; ++ch) v[ch] = *(const float4*)(xp + ch * 64);
#pragma unroll
        for (int ch = 0; ch < 12; ++ch) {
            const int cb = c16 * 4 + ch * 64;
            const int sidx = (cb >> 5) * 512 + ((((cb >> 3) & 3) * 16 + r) << 3) + (cb & 7);
            *(int2v*)&As[sidx] = (int2v){pack2(v[ch].x, v[ch].y), pack2(v[ch].z, v[ch].w)};
        }
    }
    __syncthreads();

    const short* wp0 = Wt3T + (size_t)(p0 + 0) * 12288 + lane * 8;
    const short* wp1 = Wt3T + (size_t)(p0 + 1) * 12288 + lane * 8;
    const short* wp2 = Wt3T + (size_t)(p0 + 2) * 12288 + lane * 8;

    float4v acc0 = (float4v){0.f, 0.f, 0.f, 0.f};
    float4v acc1 = acc0, acc2 = acc0;

#pragma unroll
    for (int it = 0; it < 24; ++it) {
        short8 a = *(const short8*)&As[it * 512 + lane * 8];
        short8 w0 = *(const short8*)(wp0 + it * 512);
        short8 w1 = *(const short8*)(wp1 + it * 512);
        short8 w2 = *(const short8*)(wp2 + it * 512);
        acc0 = __builtin_amdgcn_mfma_f32_16x16x32_bf16(a, w0, acc0, 0, 0, 0);
        acc1 = __builtin_amdgcn_mfma_f32_16x16x32_bf16(a, w1, acc1, 0, 0, 0);
        acc2 = __builtin_amdgcn_mfma_f32_16x16x32_bf16(a, w2, acc2, 0, 0, 0);
    }

    float4v accs[3] = {acc0, acc1, acc2};
    __syncthreads();            // all As reads complete; LDS reuse below
    short* Ks = As;             // [16][72]
    short* Vs = As + 16 * 72;   // [16][72]
#pragma unroll
    for (int t = 0; t < 3; ++t) {
        const int p = p0 + t, j = p >> 2, nt = p & 3;
        if (j == 0) {           // Q row-major (C layout: col=l16, row=quad*4+r)
#pragma unroll
            for (int r = 0; r < 4; ++r)
                Qs[(size_t)(m0 + quad * 4 + r) * 64 + nt * 16 + l16] = f2bf(accs[t][r]);
        } else {                // K, V -> LDS staging
            short* dst = (j == 1) ? Ks : Vs;
#pragma unroll
            for (int r = 0; r < 4; ++r)
                dst[(quad * 4 + r) * 72 + nt * 16 + l16] = f2bf(accs[t][r]);
        }
    }
    __syncthreads();

    if (wave < 2) {     // Kf: wave = ks half; contiguous 1KB store per wave
        short8 kfrag = *(const short8*)&Ks[l16 * 72 + wave * 32 + quad * 8];
        *(short8*)(Kf + (((size_t)(b * 256 + (s0 >> 4)) * 2 + wave) * 512) + lane * 8) = kfrag;
    } else {            // Vf: 128 threads gather the transpose
        const int t2 = tid - 128;                 // 0..127
        const int nt = t2 >> 5, lhalf = t2 & 31;
        const int halfsel = (s0 >> 4) & 1;        // which 16-kv half of the 32-kv tile
        const int lane2 = halfsel * 32 + lhalf;
        const int q2 = lhalf >> 4, l16b = lhalf & 15;
        short8 tmp;
#pragma unroll
        for (int j2 = 0; j2 < 8; ++j2)
            tmp[j2] = Vs[(q2 * 8 + j2) * 72 + nt * 16 + l16b];
        *(short8*)(Vf + (((size_t)(b * 128 + (s0 >> 5)) * 4 + nt) * 512) + lane2 * 8) = tmp;
    }
}

// ---------------- kernel 2: flash attention, frag-tiled K/V, no barriers ----
// K a-frags / V b-frags loaded as contiguous 1KB global chunks (L1/L2-resident,
// shared across waves via cache). LDS = wave-private P round-trip only.
__global__ __launch_bounds__(256, 4) void attn_kernel(
    const short* __restrict__ Qs, const short* __restrict__ Kf, const short* __restrict__ Vf,
    float* __restrict__ out, float* __restrict__ Lsum, int kv_len)
{
    __shared__ alignas(16) short Pl[4][32 * 72];    // per wave [q 32][kv 64 + 8 pad]

    const int tid = threadIdx.x;
    const int wave = tid >> 6, lane = tid & 63, quad = lane >> 4, l16 = lane & 15;
    const int qt = blockIdx.x, b = blockIdx.y, sp = blockIdx.z;
    const int q0 = qt * 128 + wave * 32;
    const int bS = b * 4096;
    const int kv0 = sp * kv_len;

    // Q frags: register layout serves as B-operand (B[k=h][n=q]) for S^T
    short8 qb[2][2];
#pragma unroll
    for (int qt2 = 0; qt2 < 2; ++qt2)
#pragma unroll
        for (int ks = 0; ks < 2; ++ks)
            qb[qt2][ks] = *(const short8*)(Qs + (size_t)(bS + q0 + qt2 * 16 + l16) * 64 + ks * 32 + quad * 8);

    float4v o[2][4];
    float rs[2] = {0.f, 0.f};
#pragma unroll
    for (int qt2 = 0; qt2 < 2; ++qt2)
#pragma unroll
        for (int nt = 0; nt < 4; ++nt) o[qt2][nt] = (float4v){0.f, 0.f, 0.f, 0.f};

    const short* kfb = Kf + (size_t)(b * 256 + (kv0 >> 4)) * 1024 + lane * 8;
    const short* vfb = Vf + (size_t)(b * 128 + (kv0 >> 5)) * 2048 + lane * 8;
    short* plw = Pl[wave];

    for (int kt = 0; kt < kv_len; kt += 64) {
        // S^T = K·Q^T per 16-kv tile; exp2; packed P write
#pragma unroll
        for (int kvt = 0; kvt < 4; ++kvt) {
            const short* kp = kfb + ((kt >> 4) + kvt) * 1024;
            short8 ka0 = *(const short8*)kp;
            short8 ka1 = *(const short8*)(kp + 512);
#pragma unroll
            for (int qt2 = 0; qt2 < 2; ++qt2) {
                float4v a0 = (float4v){0.f, 0.f, 0.f, 0.f};
                a0 = __builtin_amdgcn_mfma_f32_16x16x32_bf16(ka0, qb[qt2][0], a0, 0, 0, 0);
                a0 = __builtin_amdgcn_mfma_f32_16x16x32_bf16(ka1, qb[qt2][1], a0, 0, 0, 0);
                float p0 = fast_exp2(a0[0]), p1 = fast_exp2(a0[1]);
                float p2 = fast_exp2(a0[2]), p3 = fast_exp2(a0[3]);
                rs[qt2] += (p0 + p1) + (p2 + p3);
                *(int2v*)&plw[(qt2 * 16 + l16) * 72 + kvt * 16 + quad * 4] =
                    (int2v){pack2(p0, p1), pack2(p2, p3)};
            }
        }
        // O += P V  (V b-frags contiguous from global)
#pragma unroll
        for (int ks = 0; ks < 2; ++ks) {
            const short* vp = vfb + ((kt >> 5) + ks) * 2048;
            short8 bf[4];
#pragma unroll
            for (int nt = 0; nt < 4; ++nt)
                bf[nt] = *(const short8*)(vp + nt * 512);
#pragma unroll
            for (int qt2 = 0; qt2 < 2; ++qt2) {
                short8 af = *(const short8*)&plw[(qt2 * 16 + l16) * 72 + ks * 32 + quad * 8];
#pragma unroll
                for (int nt = 0; nt < 4; ++nt)
                    o[qt2][nt] = __builtin_amdgcn_mfma_f32_16x16x32_bf16(af, bf[nt], o[qt2][nt], 0, 0, 0);
            }
        }
    }

    // row sums: reduce across the 4 quads (same q = l16 within each qt2 tile)
#pragma unroll
    for (int qt2 = 0; qt2 < 2; ++qt2) {
        rs[qt2] += __shfl_xor(rs[qt2], 16);
        rs[qt2] += __shfl_xor(rs[qt2], 32);
    }

#pragma unroll
    for (int qt2 = 0; qt2 < 2; ++qt2) {
#pragma unroll
        for (int nt = 0; nt < 4; ++nt)
#pragma unroll
            for (int r = 0; r < 4; ++r) {
                int qb2 = q0 + qt2 * 16 + quad * 4 + r;
                atomicAdd(&out[(size_t)(bS + qb2) * 64 + nt * 16 + l16], o[qt2][nt][r]);
            }
        if (quad == 0)
            atomicAdd(&Lsum[bS + q0 + qt2 * 16 + l16], rs[qt2]);
    }
}

// ---------------- kernel 3: normalize ----------------
__global__ void normalize_kernel(float* __restrict__ out, const float* __restrict__ Lsum) {
    int idx = blockIdx.x * 256 + threadIdx.x;   // 1048576
    out[idx] /= Lsum[idx >> 6];
}

extern "C" void kernel_launch(void* const* d_in, const int* in_sizes, int n_in,
                              void* d_out, int out_size, void* d_ws, size_t ws_size,
                              hipStream_t stream) {
    const float* x  = (const float*)d_in[0];
    const float* Wk = (const float*)d_in[1];
    const float* Wq = (const float*)d_in[2];
    const float* Wv = (const float*)d_in[3];
    float* out = (float*)d_out;

    char* w = (char*)d_ws;
    size_t off = 0;
    auto take = [&](size_t bytes) -> void* {
        void* p = w + off;
        off = (off + bytes + 255) & ~(size_t)255;
        return p;
    };
    short* Qs   = (short*)take((size_t)16384 * 64 * 2);
    short* Kf   = (short*)take((size_t)16384 * 64 * 2);   // frag-tiled K
    short* Vf   = (short*)take((size_t)16384 * 64 * 2);   // frag-tiled V
    short* Wt3  = (short*)take((size_t)3 * 64 * 768 * 2);
    float* Lsum = (float*)take((size_t)16384 * 4);

    hipMemsetAsync(out, 0, (size_t)out_size * sizeof(float), stream);
    hipMemsetAsync(Lsum, 0, (size_t)16384 * 4, stream);

    wtrans_kernel<<<576, 256, 0, stream>>>(Wk, Wq, Wv, Wt3);
    proj_kernel<<<1024, 256, 0, stream>>>(x, Wt3, Qs, Kf, Vf);
    const int nsplit = 8;
    dim3 ag(32, 4, nsplit);
    attn_kernel<<<ag, 256, 0, stream>>>(Qs, Kf, Vf, out, Lsum, 4096 / nsplit);
    normalize_kernel<<<4096, 256, 0, stream>>>(out, Lsum);
}